// Round 9
// baseline (440.321 us; speedup 1.0000x reference)
//
#include <hip/hip_runtime.h>
#include <hip/hip_bf16.h>

#define E_TOT   100000
#define N_NODES 10000
#define DIMV    80
#define HID     64
#define EDIM    32
#define WNUM    2304
#define TE      64
#define NBLK    ((E_TOT + TE - 1) / TE)

static constexpr float NORMF      = 0.14433756729740643f;  // 1/sqrt(48)
static constexpr float INV_SQRT3F = 0.57735026918962576f;
static constexpr float RS32       = 0.17677669529663687f;  // 1/sqrt(32)
static constexpr float RS16       = 0.25f;                 // 1/sqrt(16)

typedef __attribute__((ext_vector_type(8))) short bf16x8;
typedef __attribute__((ext_vector_type(4))) float f32x4;

static __device__ __forceinline__ ushort f2bf(float v) {
    __hip_bfloat16 h(v);
    return *reinterpret_cast<ushort*>(&h);
}

// W2 (HID x WNUM fp32) -> W2T (WNUM x HID bf16), coalesced via LDS transpose
__global__ __launch_bounds__(256) void prep_w2t(const float* __restrict__ W2,
                                                ushort* __restrict__ W2T) {
    __shared__ float sT[64][65];
    const int j0 = blockIdx.x * 64;
    #pragma unroll
    for (int k = 0; k < 16; ++k) {
        int idx = threadIdx.x + k*256;
        int t = idx >> 6, j = idx & 63;
        sT[j][t] = W2[t*WNUM + j0 + j];
    }
    __syncthreads();
    #pragma unroll
    for (int k = 0; k < 16; ++k) {
        int idx = threadIdx.x + k*256;
        int j = idx >> 6, t = idx & 63;
        W2T[(size_t)(j0 + j)*64 + t] = f2bf(sT[j][t]);
    }
}

// W1 (EDIM x HID fp32) -> W1T (HID x EDIM bf16)
__global__ __launch_bounds__(256) void prep_w1t(const float* __restrict__ W1,
                                                ushort* __restrict__ W1T) {
    int idx = blockIdx.x*256 + threadIdx.x;   // over 64*32 = 2048
    if (idx < HID*EDIM) {
        int t = idx >> 5, i = idx & 31;
        W1T[idx] = f2bf(W1[i*HID + t]);
    }
}

// Edge kernel: block = 64 edges, 4 waves.
//  layer1 via MFMA (EA bf16 LDS x W1T) -> sHbf
//  main loop: wave-strided 36 of 144 16-col tiles; 2 B-loads feed 8 MFMA
//  (4 row-frags); 1-tile-ahead register prefetch; region epilogue into
//  per-lane partials; sX/sMsg alias one LDS pool (sX dead after K-loop).
__global__ __launch_bounds__(256) void edge_kernel(
    const int* __restrict__ dst, const float* __restrict__ x_src,
    const float* __restrict__ sh, const float* __restrict__ ea,
    const float* __restrict__ b1, const ushort* __restrict__ W1T,
    const ushort* __restrict__ W2T, const float* __restrict__ b2,
    float* __restrict__ sums, float* __restrict__ cnt)
{
    __shared__ float  sPool[TE][84];   // phase A: x rows; phase B: msg
    __shared__ float  sSh[TE][4];
    __shared__ float  sXs1[TE][17];
    __shared__ float  sEcA[TE][33];
    __shared__ ushort sHbf[TE][72];    // padded: 2-way instead of 16-way
    __shared__ ushort sEAb[TE][40];
    __shared__ int    sDst[TE];

    const int tid  = threadIdx.x;
    const int lane = tid & 63;
    const int wave = tid >> 6;
    const int e0   = blockIdx.x * TE;
    const int c    = lane & 15;
    const int g    = lane >> 4;
    const int rbase = g << 2;

    for (int i = tid; i < TE*DIMV; i += 256) {
        int e = i/80, k = i - e*80, ge = e0 + e;
        sPool[e][k] = (ge < E_TOT) ? x_src[(size_t)ge*DIMV + k] : 0.f;
    }
    for (int i = tid; i < TE*EDIM; i += 256) {
        int e = i >> 5, k = i & 31, ge = e0 + e;
        sEAb[e][k] = (ge < E_TOT) ? f2bf(ea[(size_t)ge*EDIM + k]) : (ushort)0;
    }
    for (int i = tid; i < TE*4; i += 256) {
        int e = i >> 2, k = i & 3, ge = e0 + e;
        sSh[e][k] = (ge < E_TOT) ? sh[(size_t)ge*4 + k] : 0.f;
    }
    if (tid < TE) sDst[tid] = (e0 + tid < E_TOT) ? dst[e0 + tid] : -1;
    __syncthreads();

    // ---- layer 1 via MFMA: H[64][64] = relu(EA @ W1 + b1); wave owns 16 cols
    {
        const float bv1 = b1[wave*16 + c];
        const f32x4 hinit = {bv1, bv1, bv1, bv1};
        const bf16x8 bw1 = *reinterpret_cast<const bf16x8*>(&W1T[(wave*16 + c)*EDIM + g*8]);
        #pragma unroll
        for (int eb = 0; eb < 4; ++eb) {
            bf16x8 aea = *reinterpret_cast<const bf16x8*>(&sEAb[eb*16 + c][g*8]);
            f32x4 h = __builtin_amdgcn_mfma_f32_16x16x32_bf16(aea, bw1, hinit, 0, 0, 0);
            #pragma unroll
            for (int r = 0; r < 4; ++r)
                sHbf[eb*16 + g*4 + r][wave*16 + c] = f2bf(fmaxf(h[r], 0.f));
        }
    }
    __syncthreads();

    for (int i = tid; i < TE*32; i += 256) {
        int e = i >> 5, u = i & 31;
        sEcA[e][u] = sSh[e][0] * sPool[e][u];          // cA = sh0*x0
    }
    for (int i = tid; i < TE*16; i += 256) {
        int e = i >> 4, u = i & 15;
        sXs1[e][u] = INV_SQRT3F * (sPool[e][32+u*3+0]*sSh[e][1] +
                                   sPool[e][32+u*3+1]*sSh[e][2] +
                                   sPool[e][32+u*3+2]*sSh[e][3]);
    }
    __syncthreads();

    // ---- A fragments (H rows), 4 row-tiles x 2 k-halves
    bf16x8 af[4][2];
    #pragma unroll
    for (int rt = 0; rt < 4; ++rt)
        #pragma unroll
        for (int kt = 0; kt < 2; ++kt)
            af[rt][kt] = *reinterpret_cast<const bf16x8*>(&sHbf[rt*16 + c][kt*32 + g*8]);

    float pA[16]     = {};
    float sC2[16]    = {};
    float sDv[16][3] = {};

    // ---- main loop: 36 tiles/wave, t16 = wave + 4k; 1-deep B prefetch
    bf16x8 nb0, nb1;
    float  nbv;
    {
        const ushort* bp = W2T + (((size_t)((wave << 4) + c)) << 6) + (g << 3);
        nb0 = *reinterpret_cast<const bf16x8*>(bp);
        nb1 = *reinterpret_cast<const bf16x8*>(bp + 32);
        nbv = b2[(wave << 4) + c];
    }
    #pragma unroll 4
    for (int k = 0; k < 36; ++k) {
        const bf16x8 cb0 = nb0;
        const bf16x8 cb1 = nb1;
        const float  cbv = nbv;
        if (k < 35) {
            const int t16n = wave + ((k + 1) << 2);
            const ushort* bp = W2T + (((size_t)((t16n << 4) + c)) << 6) + (g << 3);
            nb0 = *reinterpret_cast<const bf16x8*>(bp);
            nb1 = *reinterpret_cast<const bf16x8*>(bp + 32);
            nbv = b2[(t16n << 4) + c];
        }
        f32x4 acc[4];
        #pragma unroll
        for (int rt = 0; rt < 4; ++rt) {
            acc[rt] = {cbv, cbv, cbv, cbv};
            acc[rt] = __builtin_amdgcn_mfma_f32_16x16x32_bf16(af[rt][0], cb0, acc[rt], 0, 0, 0);
            acc[rt] = __builtin_amdgcn_mfma_f32_16x16x32_bf16(af[rt][1], cb1, acc[rt], 0, 0, 0);
        }
        const int t16 = wave + (k << 2);
        if (k < 16) {            // wa: j = u*32 + w, u = t16>>1
            const int u = t16 >> 1;
            #pragma unroll
            for (int rt = 0; rt < 4; ++rt)
                #pragma unroll
                for (int r = 0; r < 4; ++r)
                    pA[rt*4+r] = fmaf(sEcA[rt*16 + rbase + r][u], acc[rt][r], pA[rt*4+r]);
        } else if (k < 24) {     // wc: u = t16-64
            const int u = t16 - 64;
            #pragma unroll
            for (int rt = 0; rt < 4; ++rt)
                #pragma unroll
                for (int r = 0; r < 4; ++r)
                    sC2[rt*4+r] = fmaf(sPool[rt*16 + rbase + r][u], acc[rt][r], sC2[rt*4+r]);
        } else if (k < 28) {     // wd: u = t16-96
            const int u = t16 - 96;
            #pragma unroll
            for (int rt = 0; rt < 4; ++rt)
                #pragma unroll
                for (int r = 0; r < 4; ++r) {
                    const int e = rt*16 + rbase + r, s = rt*4 + r;
                    #pragma unroll
                    for (int m = 0; m < 3; ++m)
                        sDv[s][m] = fmaf(sPool[e][32 + u*3 + m], acc[rt][r], sDv[s][m]);
                }
        } else {                 // wb: u = (t16-112)>>1
            const int u = (t16 - 112) >> 1;
            #pragma unroll
            for (int rt = 0; rt < 4; ++rt)
                #pragma unroll
                for (int r = 0; r < 4; ++r)
                    pA[rt*4+r] = fmaf(sXs1[rt*16 + rbase + r][u], acc[rt][r], pA[rt*4+r]);
        }
    }

    // ---- sX dead; repurpose pool as msg accumulator
    __syncthreads();
    for (int i = tid; i < TE*84; i += 256) (&sPool[0][0])[i] = 0.f;
    __syncthreads();

    const int wcol = c + ((wave & 1) << 4);
    #pragma unroll
    for (int rt = 0; rt < 4; ++rt) {
        #pragma unroll
        for (int r = 0; r < 4; ++r) {
            const int e = rt*16 + rbase + r;
            const int s = rt*4 + r;
            atomicAdd(&sPool[e][wcol], pA[s]);
            const float s0 = sSh[e][0];
            atomicAdd(&sPool[e][32 + c*3 + 0], sSh[e][1]*sC2[s] + s0*sDv[s][0]);
            atomicAdd(&sPool[e][32 + c*3 + 1], sSh[e][2]*sC2[s] + s0*sDv[s][1]);
            atomicAdd(&sPool[e][32 + c*3 + 2], sSh[e][3]*sC2[s] + s0*sDv[s][2]);
        }
    }
    __syncthreads();

    for (int i = tid; i < TE*DIMV; i += 256) {
        int e = i / DIMV, k = i - e*DIMV;
        if (sDst[e] >= 0) atomicAdd(&sums[sDst[e]*DIMV + k], NORMF * sPool[e][k]);
    }
    if (tid < TE && sDst[tid] >= 0) atomicAdd(&cnt[sDst[tid]], 1.0f);
}

// Node kernel: out = residual + sums/max(cnt,1)
__global__ __launch_bounds__(256) void node_kernel(
    const float* __restrict__ x_dst, const float* __restrict__ rw0,
    const float* __restrict__ rw1, const float* __restrict__ sums,
    const float* __restrict__ cnt, float* __restrict__ out)
{
    int gid = blockIdx.x*256 + threadIdx.x;
    if (gid >= N_NODES*DIMV) return;
    int n = gid / DIMV;
    int k = gid - n*DIMV;
    const float* xd = x_dst + n*DIMV;
    float r = 0.f;
    if (k < 32) {
        #pragma unroll
        for (int u = 0; u < 32; ++u) r = fmaf(xd[u], rw0[u*32 + k], r);
        r *= RS32;
    } else {
        int kk = k - 32;
        int w = kk / 3, m = kk - w*3;
        #pragma unroll
        for (int u = 0; u < 16; ++u) r = fmaf(xd[32 + u*3 + m], rw1[u*16 + w], r);
        r *= RS16;
    }
    float cc = cnt[n];
    out[gid] = r + sums[gid] / fmaxf(cc, 1.f);
}

extern "C" void kernel_launch(void* const* d_in, const int* in_sizes, int n_in,
                              void* d_out, int out_size, void* d_ws, size_t ws_size,
                              hipStream_t stream) {
    const int*   dst   = (const int*)  d_in[0];
    const float* x_src = (const float*)d_in[1];
    const float* x_dst = (const float*)d_in[2];
    const float* sh    = (const float*)d_in[3];
    const float* ea    = (const float*)d_in[4];
    const float* W1    = (const float*)d_in[5];
    const float* b1    = (const float*)d_in[6];
    const float* W2    = (const float*)d_in[7];
    const float* b2    = (const float*)d_in[8];
    const float* rw0   = (const float*)d_in[9];
    const float* rw1   = (const float*)d_in[10];
    float* out  = (float*)d_out;
    char*  ws   = (char*)d_ws;

    float*  sums = (float*)ws;                                      // 3.2 MB
    float*  cnt  = sums + (size_t)N_NODES*DIMV;                     // 40 KB
    ushort* W2T  = (ushort*)(ws + (size_t)(N_NODES*DIMV + N_NODES)*sizeof(float));
    ushort* W1T  = W2T + (size_t)WNUM*HID;                          // +4 KB

    hipMemsetAsync(ws, 0, (size_t)(N_NODES*DIMV + N_NODES)*sizeof(float), stream);
    prep_w2t<<<WNUM/64, 256, 0, stream>>>(W2, W2T);
    prep_w1t<<<(HID*EDIM + 255)/256, 256, 0, stream>>>(W1, W1T);
    edge_kernel<<<NBLK, 256, 0, stream>>>(dst, x_src, sh, ea, b1, W1T, W2T, b2, sums, cnt);
    node_kernel<<<(N_NODES*DIMV + 255)/256, 256, 0, stream>>>(x_dst, rw0, rw1, sums, cnt, out);
}